// Round 2
// baseline (186.530 us; speedup 1.0000x reference)
//
#include <hip/hip_runtime.h>

#define NJ 24
#define ROWF 99            // 24*4 quats + 3 pos
#define BS 64
#define TT 2048
#define NROWS (BS * TT)    // 131072
#define BLOCK 256
#define NTHREADS (2 * NROWS)  // lane pair per row: even=X chain, odd=Y chain

// Row base is r*396 B -> only 4B-aligned; declare the vector type align(4)
typedef float f4_t __attribute__((ext_vector_type(4)));
typedef f4_t float4u __attribute__((aligned(4)));

__device__ __forceinline__ void quat2mat(float w, float x, float y, float z, float* R) {
  float s = 2.0f / (w*w + x*x + y*y + z*z);      // matches reference (unnormalized q)
  float xx = s*x*x, yy = s*y*y, zz = s*z*z;
  float xy = s*x*y, xz = s*x*z, yz = s*y*z;
  float xw = s*x*w, yw = s*y*w, zw = s*z*w;
  R[0] = 1.0f - (yy+zz); R[1] = xy - zw;        R[2] = xz + yw;
  R[3] = xy + zw;        R[4] = 1.0f - (xx+zz); R[5] = yz - xw;
  R[6] = xz - yw;        R[7] = yz + xw;        R[8] = 1.0f - (xx+yy);
}

__device__ __forceinline__ void mm3(const float* A, const float* B, float* C) {
#pragma unroll
  for (int r = 0; r < 3; ++r)
#pragma unroll
    for (int c = 0; c < 3; ++c)
      C[3*r+c] = fmaf(A[3*r], B[c], fmaf(A[3*r+1], B[3+c], A[3*r+2]*B[6+c]));
}

// normalized-quat squared diff vs partner lane (both lanes compute the same d^2;
// a global 0.5 factor is applied at the end)
#define QMSE(q) ({ \
  float _n  = sqrtf((q).x*(q).x + (q).y*(q).y + (q).z*(q).z + (q).w*(q).w); \
  float _iv = 1.0f / fmaxf(_n, 1e-12f); \
  float _a0 = (q).x*_iv, _a1 = (q).y*_iv, _a2 = (q).z*_iv, _a3 = (q).w*_iv; \
  float _d0 = _a0 - __shfl_xor(_a0, 1, 64); \
  float _d1 = _a1 - __shfl_xor(_a1, 1, 64); \
  float _d2 = _a2 - __shfl_xor(_a2, 1, 64); \
  float _d3 = _a3 - __shfl_xor(_a3, 1, 64); \
  _d0*_d0 + _d1*_d1 + _d2*_d2 + _d3*_d3; })

#define TDIFF(t0, t1, t2) ({ \
  float _e0 = (t0) - __shfl_xor((t0), 1, 64); \
  float _e1 = (t1) - __shfl_xor((t1), 1, 64); \
  float _e2 = (t2) - __shfl_xor((t2), 1, 64); \
  _e0*_e0 + _e1*_e1 + _e2*_e2; })

// internal joint: quat MSE + rotate-accumulate + translate + gtr diff
#define STEP(c, GP, TP, GO, TO) do { \
  float4u q = *(const float4u*)(rowp + 4*(c)); \
  rot_acc += QMSE(q); \
  float R[9]; quat2mat(q.x, q.y, q.z, q.w, R); \
  mm3(GP, R, GO); \
  float v0 = tv[3*(c)], v1 = tv[3*(c)+1], v2 = tv[3*(c)+2]; \
  TO[0] = fmaf(GP[0], v0, fmaf(GP[1], v1, fmaf(GP[2], v2, TP[0]))); \
  TO[1] = fmaf(GP[3], v0, fmaf(GP[4], v1, fmaf(GP[5], v2, TP[1]))); \
  TO[2] = fmaf(GP[6], v0, fmaf(GP[7], v1, fmaf(GP[8], v2, TP[2]))); \
  gacc += TDIFF(TO[0], TO[1], TO[2]); \
} while (0)

// leaf joint: its global rotation never feeds the loss -> skip quat2mat/mm3
#define LEAF(c, GP, TP) do { \
  float4u q = *(const float4u*)(rowp + 4*(c)); \
  rot_acc += QMSE(q); \
  float v0 = tv[3*(c)], v1 = tv[3*(c)+1], v2 = tv[3*(c)+2]; \
  float t0 = fmaf(GP[0], v0, fmaf(GP[1], v1, fmaf(GP[2], v2, TP[0]))); \
  float t1 = fmaf(GP[3], v0, fmaf(GP[4], v1, fmaf(GP[5], v2, TP[1]))); \
  float t2 = fmaf(GP[6], v0, fmaf(GP[7], v1, fmaf(GP[8], v2, TP[2]))); \
  gacc += TDIFF(t0, t1, t2); \
} while (0)

__global__ __launch_bounds__(BLOCK, 4) void motion_loss_kernel(
    const float* __restrict__ Ym, const float* __restrict__ Xm,
    const float* __restrict__ Yt, const float* __restrict__ Xt,
    float* __restrict__ out) {
  const int gtid = blockIdx.x * BLOCK + threadIdx.x;
  const int r   = gtid >> 1;          // row (b,t)
  const int par = gtid & 1;           // 0 = X chain, 1 = Y chain
  const float* __restrict__ rowp = (par ? Ym : Xm) + (size_t)r * ROWF;
  const int b = r >> 11;              // r / TT; wave spans 32 rows, never crosses b
  const float* __restrict__ tv = (par ? Yt : Xt) + (size_t)b * NJ * 3;

  float rot_acc = 0.0f, gacc = 0.0f;
  float GA[9], GB[9], GC[9], GD[9];
  float TA[3], TB[3], TC[3], TD[3];

  // root: gtr0 == raw position; feeds both the gtr term and the pos term
  float4u q0 = *(const float4u*)(rowp);
  rot_acc += QMSE(q0);
  quat2mat(q0.x, q0.y, q0.z, q0.w, GA);
  TA[0] = rowp[96]; TA[1] = rowp[97]; TA[2] = rowp[98];
  float rootd2 = TDIFF(TA[0], TA[1], TA[2]);
  gacc += rootd2;

  // BFS (index) order; 4-slot sliding register window (liveness-verified).
  // TOPOLOGY = [-1,0,0,0,1,2,3,4,5,6,7,8,9,9,9,12,13,14,16,17,18,19,20,21]
  STEP(1,  GA, TA, GB, TB);
  STEP(2,  GA, TA, GC, TC);
  STEP(3,  GA, TA, GD, TD);
  STEP(4,  GB, TB, GA, TA);
  STEP(5,  GC, TC, GB, TB);
  STEP(6,  GD, TD, GC, TC);
  STEP(7,  GA, TA, GD, TD);
  STEP(8,  GB, TB, GA, TA);
  STEP(9,  GC, TC, GB, TB);
  LEAF(10, GD, TD);
  LEAF(11, GA, TA);
  STEP(12, GB, TB, GC, TC);
  STEP(13, GB, TB, GD, TD);
  STEP(14, GB, TB, GA, TA);
  LEAF(15, GC, TC);
  STEP(16, GD, TD, GB, TB);
  STEP(17, GA, TA, GC, TC);
  STEP(18, GB, TB, GD, TD);
  STEP(19, GC, TC, GA, TA);
  STEP(20, GD, TD, GB, TB);
  STEP(21, GA, TA, GC, TC);
  LEAF(22, GB, TB);
  LEAF(23, GC, TC);

  const float c_rot = 1.0f / ((float)NROWS * NJ * 4);   // B1 * mean over (bs,T,24,4)
  const float c_gtr = 2.5f / ((float)NROWS * NJ * 3);   // B2*2.5 * mean over (bs,T,24,3)
  const float c_pos = 1.0f / ((float)NROWS * 3);        // B2 * mean over (bs,T,3)
  // 0.5: both lanes of a pair accumulated identical squared diffs
  float contrib = 0.5f * (c_rot * rot_acc + c_gtr * gacc + c_pos * rootd2);
#pragma unroll
  for (int o = 32; o > 0; o >>= 1) contrib += __shfl_down(contrib, o, 64);
  if ((threadIdx.x & 63) == 0) atomicAdd(out, contrib);
}

extern "C" void kernel_launch(void* const* d_in, const int* in_sizes, int n_in,
                              void* d_out, int out_size, void* d_ws, size_t ws_size,
                              hipStream_t stream) {
  const float* Ym = (const float*)d_in[0];
  const float* Xm = (const float*)d_in[1];
  const float* Yt = (const float*)d_in[2];
  const float* Xt = (const float*)d_in[3];
  float* out = (float*)d_out;
  hipMemsetAsync(out, 0, sizeof(float), stream);
  motion_loss_kernel<<<NTHREADS / BLOCK, BLOCK, 0, stream>>>(Ym, Xm, Yt, Xt, out);
}